// Round 1
// baseline (5999.375 us; speedup 1.0000x reference)
//
#include <hip/hip_runtime.h>
#include <hip/hip_bf16.h>

// ---------------------------------------------------------------------------
// Encoder block (graph-transformer style), fp32 correctness baseline.
// B=8, N=128, DIM=256, HEADS=8, dk=32, HID=1024.
// Row space for edge tensors: R = 131072 rows of 256 channels.
// ---------------------------------------------------------------------------

#define DIMC 256
#define NSEQ 128
#define NB 8
#define HID 1024
#define EROWS (NB * NSEQ * NSEQ)   // 131072

__device__ __forceinline__ float block_reduce_sum(float v, float* sc, int t) {
    #pragma unroll
    for (int o = 32; o > 0; o >>= 1) v += __shfl_down(v, o, 64);
    __syncthreads();                 // protect sc reuse across consecutive calls
    if ((t & 63) == 0) sc[t >> 6] = v;
    __syncthreads();
    return sc[0] + sc[1] + sc[2] + sc[3];
}

// ---------------------------------------------------------------------------
// Kernel 1: x1 = LN1(x); q/k/v = x1 @ W{q,k,v} + b.  One block per (b,i) row.
// ---------------------------------------------------------------------------
__global__ __launch_bounds__(256, 2) void k_ln_qkv(
    const float* __restrict__ X, const float* __restrict__ g, const float* __restrict__ be,
    const float* __restrict__ Wq, const float* __restrict__ bq,
    const float* __restrict__ Wk, const float* __restrict__ bk,
    const float* __restrict__ Wv, const float* __restrict__ bv,
    float* __restrict__ X1, float* __restrict__ Q, float* __restrict__ K, float* __restrict__ V)
{
    __shared__ float xs[DIMC];
    __shared__ float red[4];
    const int t = threadIdx.x;
    const int row = blockIdx.x;
    float v = X[(size_t)row * DIMC + t];
    float mu = block_reduce_sum(v, red, t) * (1.f / DIMC);
    float d = v - mu;
    float var = block_reduce_sum(d * d, red, t) * (1.f / DIMC);
    float x1v = d * rsqrtf(var + 1e-5f) * g[t] + be[t];
    xs[t] = x1v;
    X1[(size_t)row * DIMC + t] = x1v;
    __syncthreads();
    float aq = bq[t], ak = bk[t], av = bv[t];
    #pragma unroll 4
    for (int k2 = 0; k2 < DIMC; ++k2) {
        float xv = xs[k2];
        aq = fmaf(xv, Wq[k2 * DIMC + t], aq);
        ak = fmaf(xv, Wk[k2 * DIMC + t], ak);
        av = fmaf(xv, Wv[k2 * DIMC + t], av);
    }
    Q[(size_t)row * DIMC + t] = aq;
    K[(size_t)row * DIMC + t] = ak;
    V[(size_t)row * DIMC + t] = av;
}

// ---------------------------------------------------------------------------
// Tiled fp32 GEMM 64x64x16, 256 threads, 4x4 micro-tile. Two instances with
// different epilogues (e->attn fuse, edge bias).
// ---------------------------------------------------------------------------
#define BM 64
#define BN 64
#define BK 16

// e = Y @ We + be ; attn = (q*k/sqrt(32)) * (e+1) * e   -> ATT
__global__ __launch_bounds__(256, 2) void k_e_attn(
    const float* __restrict__ A,    // Y, EROWS x 256
    const float* __restrict__ B,    // We, 256 x 256
    const float* __restrict__ bias, // be
    const float* __restrict__ Q, const float* __restrict__ Kp,
    float* __restrict__ ATT)
{
    __shared__ float As[BK][BM + 4];
    __shared__ float Bs[BK][BN + 4];
    const int t = threadIdx.x;
    const int tx = t & 15, ty = t >> 4;
    const int m0 = blockIdx.x * BM, n0 = blockIdx.y * BN;
    float acc[4][4] = {};
    for (int kk = 0; kk < DIMC; kk += BK) {
        const int r = t >> 2, kc = (t & 3) * 4;
        float4 a4 = *(const float4*)&A[(size_t)(m0 + r) * DIMC + kk + kc];
        As[kc + 0][r] = a4.x; As[kc + 1][r] = a4.y; As[kc + 2][r] = a4.z; As[kc + 3][r] = a4.w;
        const int kb = t >> 4, nb = (t & 15) * 4;
        *(float4*)&Bs[kb][nb] = *(const float4*)&B[(size_t)(kk + kb) * DIMC + n0 + nb];
        __syncthreads();
        #pragma unroll
        for (int k2 = 0; k2 < BK; ++k2) {
            float4 a = *(const float4*)&As[k2][ty * 4];
            float4 b = *(const float4*)&Bs[k2][tx * 4];
            float am[4] = {a.x, a.y, a.z, a.w};
            float bn[4] = {b.x, b.y, b.z, b.w};
            #pragma unroll
            for (int mm = 0; mm < 4; ++mm)
                #pragma unroll
                for (int nn = 0; nn < 4; ++nn)
                    acc[mm][nn] = fmaf(am[mm], bn[nn], acc[mm][nn]);
        }
        __syncthreads();
    }
    const float inv_sqrt_dk = 0.17677669529663687f;  // 1/sqrt(32)
    #pragma unroll
    for (int mm = 0; mm < 4; ++mm) {
        const int m = m0 + ty * 4 + mm;
        const int qrow = m >> 7;                         // b*128 + i
        const int krow = ((m >> 14) << 7) | (m & 127);   // b*128 + j
        #pragma unroll
        for (int nn = 0; nn < 4; ++nn) {
            const int n = n0 + tx * 4 + nn;
            float e = acc[mm][nn] + bias[n];
            float qk = Q[(size_t)qrow * DIMC + n] * Kp[(size_t)krow * DIMC + n] * inv_sqrt_dk;
            ATT[(size_t)m * DIMC + n] = qk * (e + 1.f) * e;
        }
    }
}

// EDGE = ATT @ Woe + boe   -> written into d_out y-region (scratch)
__global__ __launch_bounds__(256, 2) void k_edge(
    const float* __restrict__ A,    // ATT
    const float* __restrict__ B,    // Woe
    const float* __restrict__ bias, // boe
    float* __restrict__ EDGE)
{
    __shared__ float As[BK][BM + 4];
    __shared__ float Bs[BK][BN + 4];
    const int t = threadIdx.x;
    const int tx = t & 15, ty = t >> 4;
    const int m0 = blockIdx.x * BM, n0 = blockIdx.y * BN;
    float acc[4][4] = {};
    for (int kk = 0; kk < DIMC; kk += BK) {
        const int r = t >> 2, kc = (t & 3) * 4;
        float4 a4 = *(const float4*)&A[(size_t)(m0 + r) * DIMC + kk + kc];
        As[kc + 0][r] = a4.x; As[kc + 1][r] = a4.y; As[kc + 2][r] = a4.z; As[kc + 3][r] = a4.w;
        const int kb = t >> 4, nb = (t & 15) * 4;
        *(float4*)&Bs[kb][nb] = *(const float4*)&B[(size_t)(kk + kb) * DIMC + n0 + nb];
        __syncthreads();
        #pragma unroll
        for (int k2 = 0; k2 < BK; ++k2) {
            float4 a = *(const float4*)&As[k2][ty * 4];
            float4 b = *(const float4*)&Bs[k2][tx * 4];
            float am[4] = {a.x, a.y, a.z, a.w};
            float bn[4] = {b.x, b.y, b.z, b.w};
            #pragma unroll
            for (int mm = 0; mm < 4; ++mm)
                #pragma unroll
                for (int nn = 0; nn < 4; ++nn)
                    acc[mm][nn] = fmaf(am[mm], bn[nn], acc[mm][nn]);
        }
        __syncthreads();
    }
    #pragma unroll
    for (int mm = 0; mm < 4; ++mm) {
        const int m = m0 + ty * 4 + mm;
        #pragma unroll
        for (int nn = 0; nn < 4; ++nn) {
            const int n = n0 + tx * 4 + nn;
            EDGE[(size_t)m * DIMC + n] = acc[mm][nn] + bias[n];
        }
    }
}

// ---------------------------------------------------------------------------
// Kernel 4: x-path tail. One block per (b,i). Online softmax over j +
// weighted-v sum, Won GEMV, LN3, MLP(256->1024->256), LN5 -> x_out.
// ---------------------------------------------------------------------------
__global__ __launch_bounds__(256, 2) void k_node_x(
    const float* __restrict__ ATT, const float* __restrict__ V,
    const float* __restrict__ X1,
    const float* __restrict__ Won, const float* __restrict__ bon,
    const float* __restrict__ g3, const float* __restrict__ b3,
    const float* __restrict__ W1, const float* __restrict__ b1,
    const float* __restrict__ W2, const float* __restrict__ b2,
    const float* __restrict__ g5, const float* __restrict__ b5,
    float* __restrict__ OUTX)
{
    __shared__ float ns[DIMC];
    __shared__ float x2s[DIMC];
    __shared__ float hs[HID];
    __shared__ float red[4];
    const int t = threadIdx.x;
    const int bi = blockIdx.x;          // b*128 + i
    const int b = bi >> 7;
    const float* arow = ATT + (size_t)bi * NSEQ * DIMC + t;
    const float* vbase = V + (size_t)b * NSEQ * DIMC + t;
    float mx = -3.4e38f, l = 0.f, acc = 0.f;
    for (int j = 0; j < NSEQ; ++j) {
        float a = arow[(size_t)j * DIMC];
        float vv = vbase[(size_t)j * DIMC];
        if (a > mx) { float sc = __expf(mx - a); l *= sc; acc *= sc; mx = a; }
        float p = __expf(a - mx);
        l += p;
        acc = fmaf(p, vv, acc);
    }
    ns[t] = acc / l;
    __syncthreads();
    float o = bon[t];
    #pragma unroll 4
    for (int k2 = 0; k2 < DIMC; ++k2) o = fmaf(ns[k2], Won[k2 * DIMC + t], o);
    float resid = X1[(size_t)bi * DIMC + t] + o;
    float mu = block_reduce_sum(resid, red, t) * (1.f / DIMC);
    float d = resid - mu;
    float var = block_reduce_sum(d * d, red, t) * (1.f / DIMC);
    float x2 = d * rsqrtf(var + 1e-5f) * g3[t] + b3[t];
    x2s[t] = x2;
    __syncthreads();
    float4 h = *(const float4*)&b1[t * 4];
    for (int k2 = 0; k2 < DIMC; ++k2) {
        float xv = x2s[k2];
        float4 w = *(const float4*)&W1[(size_t)k2 * HID + t * 4];
        h.x = fmaf(xv, w.x, h.x); h.y = fmaf(xv, w.y, h.y);
        h.z = fmaf(xv, w.z, h.z); h.w = fmaf(xv, w.w, h.w);
    }
    h.x = fmaxf(h.x, 0.f); h.y = fmaxf(h.y, 0.f); h.z = fmaxf(h.z, 0.f); h.w = fmaxf(h.w, 0.f);
    *(float4*)&hs[t * 4] = h;
    __syncthreads();
    float o2 = b2[t];
    #pragma unroll 4
    for (int hh = 0; hh < HID; ++hh) o2 = fmaf(hs[hh], W2[(size_t)hh * DIMC + t], o2);
    float r2 = x2 + o2;
    float mu2 = block_reduce_sum(r2, red, t) * (1.f / DIMC);
    float d2 = r2 - mu2;
    float v2 = block_reduce_sum(d2 * d2, red, t) * (1.f / DIMC);
    OUTX[(size_t)bi * DIMC + t] = d2 * rsqrtf(v2 + 1e-5f) * g5[t] + b5[t];
}

// ---------------------------------------------------------------------------
// Kernel 5: y-path tail. One block per 32 edge-rows. y2 = LN4(edge + y);
// y_out = LN6(y2 + MLP(y2)), hidden chunked by 32 (never materialized).
// EDGE is read from and OUTY written to the SAME d_out region (in-place,
// block-local rows only).
// ---------------------------------------------------------------------------
__global__ __launch_bounds__(256, 2) void k_mlp_y(
    float* __restrict__ EY,          // d_out y-region: in=edge, out=y_out
    const float* __restrict__ Y,
    const float* __restrict__ g4, const float* __restrict__ b4,
    const float* __restrict__ W1, const float* __restrict__ b1,
    const float* __restrict__ W2, const float* __restrict__ b2,
    const float* __restrict__ g6, const float* __restrict__ b6)
{
    __shared__ float As[32][DIMC + 1];   // y2 tile
    __shared__ float W1s[DIMC][33];      // W1 chunk [k][j]
    __shared__ float Hs[32][33];         // relu(hidden) chunk
    __shared__ float red[4];
    const int t = threadIdx.x;
    const size_t R0 = (size_t)blockIdx.x * 32;

    // Load residual (edge + y) into LDS, coalesced + pipelined.
    for (int idx = t; idx < 32 * DIMC; idx += 256) {
        const int r = idx >> 8, c = idx & 255;
        As[r][c] = EY[(R0 + r) * DIMC + c] + Y[(R0 + r) * DIMC + c];
    }
    __syncthreads();
    // LN4 per row (in LDS).
    for (int r = 0; r < 32; ++r) {
        float v = As[r][t];
        float mu = block_reduce_sum(v, red, t) * (1.f / DIMC);
        float d = v - mu;
        float var = block_reduce_sum(d * d, red, t) * (1.f / DIMC);
        As[r][t] = d * rsqrtf(var + 1e-5f) * g4[t] + b4[t];
    }
    __syncthreads();

    float out[32];
    #pragma unroll
    for (int r = 0; r < 32; ++r) out[r] = 0.f;
    const int j = t & 31, rg = t >> 5;       // rg in 0..7
    const int r4 = rg * 4;
    for (int hh = 0; hh < 32; ++hh) {        // hidden chunks of 32
        // stage W1[:, hh*32 .. +31] into LDS
        #pragma unroll 4
        for (int kk2 = 0; kk2 < 32; ++kk2) {
            const int k2 = kk2 * 8 + rg;
            W1s[k2][j] = W1[(size_t)k2 * HID + hh * 32 + j];
        }
        __syncthreads();
        // GEMM1: H[r4+rr][j] = relu(As[r4+rr][:] . W1s[:][j] + b1)
        float hacc[4];
        {
            const float bb = b1[hh * 32 + j];
            hacc[0] = bb; hacc[1] = bb; hacc[2] = bb; hacc[3] = bb;
        }
        #pragma unroll 4
        for (int k2 = 0; k2 < DIMC; ++k2) {
            const float w = W1s[k2][j];
            #pragma unroll
            for (int rr = 0; rr < 4; ++rr)
                hacc[rr] = fmaf(As[r4 + rr][k2], w, hacc[rr]);
        }
        #pragma unroll
        for (int rr = 0; rr < 4; ++rr) Hs[r4 + rr][j] = fmaxf(hacc[rr], 0.f);
        __syncthreads();
        // GEMM2: out[r] += Hs[r][jj] * W2[hh*32+jj][t]
        #pragma unroll 4
        for (int jj = 0; jj < 32; ++jj) {
            const float w2 = W2[(size_t)(hh * 32 + jj) * DIMC + t];
            #pragma unroll
            for (int r = 0; r < 32; ++r) out[r] = fmaf(Hs[r][jj], w2, out[r]);
        }
        __syncthreads();   // before overwriting W1s/Hs next chunk
    }

    // Residual + LN6, write final y_out in place.
    const float bb2 = b2[t];
    for (int r = 0; r < 32; ++r) {
        float v = As[r][t] + out[r] + bb2;
        float mu = block_reduce_sum(v, red, t) * (1.f / DIMC);
        float d = v - mu;
        float var = block_reduce_sum(d * d, red, t) * (1.f / DIMC);
        EY[(R0 + r) * DIMC + t] = d * rsqrtf(var + 1e-5f) * g6[t] + b6[t];
    }
}

// ---------------------------------------------------------------------------
extern "C" void kernel_launch(void* const* d_in, const int* in_sizes, int n_in,
                              void* d_out, int out_size, void* d_ws, size_t ws_size,
                              hipStream_t stream) {
    const float* x    = (const float*)d_in[0];
    const float* y    = (const float*)d_in[1];
    // d_in[2] = heads (constant 8, unused)
    const float* Wq   = (const float*)d_in[3];  const float* bq  = (const float*)d_in[4];
    const float* Wk   = (const float*)d_in[5];  const float* bk  = (const float*)d_in[6];
    const float* Wv   = (const float*)d_in[7];  const float* bv  = (const float*)d_in[8];
    const float* We   = (const float*)d_in[9];  const float* be  = (const float*)d_in[10];
    const float* Woe  = (const float*)d_in[11]; const float* boe = (const float*)d_in[12];
    const float* Won  = (const float*)d_in[13]; const float* bon = (const float*)d_in[14];
    const float* ln1g = (const float*)d_in[15]; const float* ln1b = (const float*)d_in[16];
    const float* ln3g = (const float*)d_in[17]; const float* ln3b = (const float*)d_in[18];
    const float* ln4g = (const float*)d_in[19]; const float* ln4b = (const float*)d_in[20];
    const float* ln5g = (const float*)d_in[21]; const float* ln5b = (const float*)d_in[22];
    const float* ln6g = (const float*)d_in[23]; const float* ln6b = (const float*)d_in[24];
    const float* m1W1 = (const float*)d_in[25]; const float* m1b1 = (const float*)d_in[26];
    const float* m1W2 = (const float*)d_in[27]; const float* m1b2 = (const float*)d_in[28];
    const float* m2W1 = (const float*)d_in[29]; const float* m2b1 = (const float*)d_in[30];
    const float* m2W2 = (const float*)d_in[31]; const float* m2b2 = (const float*)d_in[32];

    float* outx = (float*)d_out;                       // (8,128,256)
    float* outy = (float*)d_out + NB * NSEQ * DIMC;    // (8,128,128,256)

    float* ws  = (float*)d_ws;
    float* X1  = ws;                    //  262144 floats
    float* Q   = ws + 262144;
    float* K   = ws + 524288;
    float* V   = ws + 786432;
    float* ATT = ws + 1048576;          //  33554432 floats (134 MB)

    k_ln_qkv<<<NB * NSEQ, 256, 0, stream>>>(x, ln1g, ln1b, Wq, bq, Wk, bk, Wv, bv, X1, Q, K, V);
    k_e_attn<<<dim3(EROWS / BM, DIMC / BN), 256, 0, stream>>>(y, We, be, Q, K, ATT);
    k_edge<<<dim3(EROWS / BM, DIMC / BN), 256, 0, stream>>>(ATT, Woe, boe, outy);
    k_node_x<<<NB * NSEQ, 256, 0, stream>>>(ATT, V, X1, Won, bon, ln3g, ln3b,
                                            m1W1, m1b1, m1W2, m1b2, ln5g, ln5b, outx);
    k_mlp_y<<<EROWS / 32, 256, 0, stream>>>(outy, y, ln4g, ln4b,
                                            m2W1, m2b1, m2W2, m2b2, ln6g, ln6b);
}

// Round 2
// 1435.539 us; speedup vs baseline: 4.1792x; 4.1792x over previous
//
#include <hip/hip_runtime.h>
#include <hip/hip_bf16.h>

// ---------------------------------------------------------------------------
// Encoder block. B=8, N=128, DIM=256, HEADS=8, dk=32, HID=1024.
// R2: y-path MLP tail rewritten as fused bf16 MFMA (32x32x16) kernel.
// ---------------------------------------------------------------------------

#define DIMC 256
#define NSEQ 128
#define NB 8
#define HID 1024
#define EROWS (NB * NSEQ * NSEQ)   // 131072

typedef __attribute__((ext_vector_type(8)))  short short8;
typedef __attribute__((ext_vector_type(16))) float f32x16;

__device__ __forceinline__ short f2bf(float f) {
    union { float f; unsigned u; } v; v.f = f;
    unsigned r = (v.u + 0x7FFF + ((v.u >> 16) & 1)) >> 16;
    return (short)r;
}
__device__ __forceinline__ float bf2f(short s) {
    union { unsigned u; float f; } v; v.u = ((unsigned)(unsigned short)s) << 16;
    return v.f;
}

__device__ __forceinline__ float wave_sum(float v) {
    #pragma unroll
    for (int o = 32; o; o >>= 1) v += __shfl_xor(v, o, 64);
    return v;
}

__device__ __forceinline__ float block_reduce_sum(float v, float* sc, int t) {
    #pragma unroll
    for (int o = 32; o > 0; o >>= 1) v += __shfl_down(v, o, 64);
    __syncthreads();
    if ((t & 63) == 0) sc[t >> 6] = v;
    __syncthreads();
    return sc[0] + sc[1] + sc[2] + sc[3];
}

// ---------------------------------------------------------------------------
// Kernel 1: x1 = LN1(x); q/k/v = x1 @ W{q,k,v} + b.  One block per (b,i) row.
// ---------------------------------------------------------------------------
__global__ __launch_bounds__(256, 2) void k_ln_qkv(
    const float* __restrict__ X, const float* __restrict__ g, const float* __restrict__ be,
    const float* __restrict__ Wq, const float* __restrict__ bq,
    const float* __restrict__ Wk, const float* __restrict__ bk,
    const float* __restrict__ Wv, const float* __restrict__ bv,
    float* __restrict__ X1, float* __restrict__ Q, float* __restrict__ K, float* __restrict__ V)
{
    __shared__ float xs[DIMC];
    __shared__ float red[4];
    const int t = threadIdx.x;
    const int row = blockIdx.x;
    float v = X[(size_t)row * DIMC + t];
    float mu = block_reduce_sum(v, red, t) * (1.f / DIMC);
    float d = v - mu;
    float var = block_reduce_sum(d * d, red, t) * (1.f / DIMC);
    float x1v = d * rsqrtf(var + 1e-5f) * g[t] + be[t];
    xs[t] = x1v;
    X1[(size_t)row * DIMC + t] = x1v;
    __syncthreads();
    float aq = bq[t], ak = bk[t], av = bv[t];
    #pragma unroll 4
    for (int k2 = 0; k2 < DIMC; ++k2) {
        float xv = xs[k2];
        aq = fmaf(xv, Wq[k2 * DIMC + t], aq);
        ak = fmaf(xv, Wk[k2 * DIMC + t], ak);
        av = fmaf(xv, Wv[k2 * DIMC + t], av);
    }
    Q[(size_t)row * DIMC + t] = aq;
    K[(size_t)row * DIMC + t] = ak;
    V[(size_t)row * DIMC + t] = av;
}

// ---------------------------------------------------------------------------
// Tiled fp32 GEMM 64x64x16 (unchanged this round).
// ---------------------------------------------------------------------------
#define BM 64
#define BN 64
#define BK 16

__global__ __launch_bounds__(256, 2) void k_e_attn(
    const float* __restrict__ A, const float* __restrict__ B,
    const float* __restrict__ bias,
    const float* __restrict__ Q, const float* __restrict__ Kp,
    float* __restrict__ ATT)
{
    __shared__ float As[BK][BM + 4];
    __shared__ float Bs[BK][BN + 4];
    const int t = threadIdx.x;
    const int tx = t & 15, ty = t >> 4;
    const int m0 = blockIdx.x * BM, n0 = blockIdx.y * BN;
    float acc[4][4] = {};
    for (int kk = 0; kk < DIMC; kk += BK) {
        const int r = t >> 2, kc = (t & 3) * 4;
        float4 a4 = *(const float4*)&A[(size_t)(m0 + r) * DIMC + kk + kc];
        As[kc + 0][r] = a4.x; As[kc + 1][r] = a4.y; As[kc + 2][r] = a4.z; As[kc + 3][r] = a4.w;
        const int kb = t >> 4, nb = (t & 15) * 4;
        *(float4*)&Bs[kb][nb] = *(const float4*)&B[(size_t)(kk + kb) * DIMC + n0 + nb];
        __syncthreads();
        #pragma unroll
        for (int k2 = 0; k2 < BK; ++k2) {
            float4 a = *(const float4*)&As[k2][ty * 4];
            float4 b = *(const float4*)&Bs[k2][tx * 4];
            float am[4] = {a.x, a.y, a.z, a.w};
            float bn[4] = {b.x, b.y, b.z, b.w};
            #pragma unroll
            for (int mm = 0; mm < 4; ++mm)
                #pragma unroll
                for (int nn = 0; nn < 4; ++nn)
                    acc[mm][nn] = fmaf(am[mm], bn[nn], acc[mm][nn]);
        }
        __syncthreads();
    }
    const float inv_sqrt_dk = 0.17677669529663687f;
    #pragma unroll
    for (int mm = 0; mm < 4; ++mm) {
        const int m = m0 + ty * 4 + mm;
        const int qrow = m >> 7;
        const int krow = ((m >> 14) << 7) | (m & 127);
        #pragma unroll
        for (int nn = 0; nn < 4; ++nn) {
            const int n = n0 + tx * 4 + nn;
            float e = acc[mm][nn] + bias[n];
            float qk = Q[(size_t)qrow * DIMC + n] * Kp[(size_t)krow * DIMC + n] * inv_sqrt_dk;
            ATT[(size_t)m * DIMC + n] = qk * (e + 1.f) * e;
        }
    }
}

__global__ __launch_bounds__(256, 2) void k_edge(
    const float* __restrict__ A, const float* __restrict__ B,
    const float* __restrict__ bias, float* __restrict__ EDGE)
{
    __shared__ float As[BK][BM + 4];
    __shared__ float Bs[BK][BN + 4];
    const int t = threadIdx.x;
    const int tx = t & 15, ty = t >> 4;
    const int m0 = blockIdx.x * BM, n0 = blockIdx.y * BN;
    float acc[4][4] = {};
    for (int kk = 0; kk < DIMC; kk += BK) {
        const int r = t >> 2, kc = (t & 3) * 4;
        float4 a4 = *(const float4*)&A[(size_t)(m0 + r) * DIMC + kk + kc];
        As[kc + 0][r] = a4.x; As[kc + 1][r] = a4.y; As[kc + 2][r] = a4.z; As[kc + 3][r] = a4.w;
        const int kb = t >> 4, nb = (t & 15) * 4;
        *(float4*)&Bs[kb][nb] = *(const float4*)&B[(size_t)(kk + kb) * DIMC + n0 + nb];
        __syncthreads();
        #pragma unroll
        for (int k2 = 0; k2 < BK; ++k2) {
            float4 a = *(const float4*)&As[k2][ty * 4];
            float4 b = *(const float4*)&Bs[k2][tx * 4];
            float am[4] = {a.x, a.y, a.z, a.w};
            float bn[4] = {b.x, b.y, b.z, b.w};
            #pragma unroll
            for (int mm = 0; mm < 4; ++mm)
                #pragma unroll
                for (int nn = 0; nn < 4; ++nn)
                    acc[mm][nn] = fmaf(am[mm], bn[nn], acc[mm][nn]);
        }
        __syncthreads();
    }
    #pragma unroll
    for (int mm = 0; mm < 4; ++mm) {
        const int m = m0 + ty * 4 + mm;
        #pragma unroll
        for (int nn = 0; nn < 4; ++nn) {
            const int n = n0 + tx * 4 + nn;
            EDGE[(size_t)m * DIMC + n] = acc[mm][nn] + bias[n];
        }
    }
}

// ---------------------------------------------------------------------------
// Kernel 4: x-path tail (unchanged this round).
// ---------------------------------------------------------------------------
__global__ __launch_bounds__(256, 2) void k_node_x(
    const float* __restrict__ ATT, const float* __restrict__ V,
    const float* __restrict__ X1,
    const float* __restrict__ Won, const float* __restrict__ bon,
    const float* __restrict__ g3, const float* __restrict__ b3,
    const float* __restrict__ W1, const float* __restrict__ b1,
    const float* __restrict__ W2, const float* __restrict__ b2,
    const float* __restrict__ g5, const float* __restrict__ b5,
    float* __restrict__ OUTX)
{
    __shared__ float ns[DIMC];
    __shared__ float x2s[DIMC];
    __shared__ float hs[HID];
    __shared__ float red[4];
    const int t = threadIdx.x;
    const int bi = blockIdx.x;
    const int b = bi >> 7;
    const float* arow = ATT + (size_t)bi * NSEQ * DIMC + t;
    const float* vbase = V + (size_t)b * NSEQ * DIMC + t;
    float mx = -3.4e38f, l = 0.f, acc = 0.f;
    for (int j = 0; j < NSEQ; ++j) {
        float a = arow[(size_t)j * DIMC];
        float vv = vbase[(size_t)j * DIMC];
        if (a > mx) { float sc = __expf(mx - a); l *= sc; acc *= sc; mx = a; }
        float p = __expf(a - mx);
        l += p;
        acc = fmaf(p, vv, acc);
    }
    ns[t] = acc / l;
    __syncthreads();
    float o = bon[t];
    #pragma unroll 4
    for (int k2 = 0; k2 < DIMC; ++k2) o = fmaf(ns[k2], Won[k2 * DIMC + t], o);
    float resid = X1[(size_t)bi * DIMC + t] + o;
    float mu = block_reduce_sum(resid, red, t) * (1.f / DIMC);
    float d = resid - mu;
    float var = block_reduce_sum(d * d, red, t) * (1.f / DIMC);
    float x2 = d * rsqrtf(var + 1e-5f) * g3[t] + b3[t];
    x2s[t] = x2;
    __syncthreads();
    float4 h = *(const float4*)&b1[t * 4];
    for (int k2 = 0; k2 < DIMC; ++k2) {
        float xv = x2s[k2];
        float4 w = *(const float4*)&W1[(size_t)k2 * HID + t * 4];
        h.x = fmaf(xv, w.x, h.x); h.y = fmaf(xv, w.y, h.y);
        h.z = fmaf(xv, w.z, h.z); h.w = fmaf(xv, w.w, h.w);
    }
    h.x = fmaxf(h.x, 0.f); h.y = fmaxf(h.y, 0.f); h.z = fmaxf(h.z, 0.f); h.w = fmaxf(h.w, 0.f);
    *(float4*)&hs[t * 4] = h;
    __syncthreads();
    float o2 = b2[t];
    #pragma unroll 4
    for (int hh = 0; hh < HID; ++hh) o2 = fmaf(hs[hh], W2[(size_t)hh * DIMC + t], o2);
    float r2 = x2 + o2;
    float mu2 = block_reduce_sum(r2, red, t) * (1.f / DIMC);
    float d2 = r2 - mu2;
    float v2 = block_reduce_sum(d2 * d2, red, t) * (1.f / DIMC);
    OUTX[(size_t)bi * DIMC + t] = d2 * rsqrtf(v2 + 1e-5f) * g5[t] + b5[t];
}

// ---------------------------------------------------------------------------
// Transpose + fp32->bf16 convert: dst[N][M] = bf16(src[M][N]).
// ---------------------------------------------------------------------------
__global__ __launch_bounds__(256) void k_transpose_bf16(
    const float* __restrict__ src, short* __restrict__ dst, int M, int N)
{
    __shared__ short tile[32][33];
    const int t = threadIdx.x, tx = t & 31, ty = t >> 5;
    const int bx = blockIdx.x, by = blockIdx.y;
    #pragma unroll
    for (int r = ty; r < 32; r += 8)
        tile[r][tx] = f2bf(src[(size_t)(by * 32 + r) * N + bx * 32 + tx]);
    __syncthreads();
    #pragma unroll
    for (int r = ty; r < 32; r += 8)
        dst[(size_t)(bx * 32 + r) * M + by * 32 + tx] = tile[tx][r];
}

// ---------------------------------------------------------------------------
// Kernel 5 (R2): fused y-path tail with bf16 MFMA.
//   y2 = LN4(edge+y) -> bf16 in LDS (xor-swizzled 8-elem groups)
//   16 hidden chunks of 64: H = relu(y2@W1+b1) via 32x32x16 MFMA,
//                           out += H@W2 (acc in 64 VGPRs/lane)
//   y_out = LN6(y2 + out + b2), in-place over EY.
// W1T [1024][256], W2T [256][1024] are pre-transposed bf16 (B-frags read
// straight from global; W1T+W2T = 1 MB -> L2-resident).
// ---------------------------------------------------------------------------
__global__ __launch_bounds__(256, 2) void k_mlp_y2(
    float* __restrict__ EY, const float* __restrict__ Y,
    const float* __restrict__ g4, const float* __restrict__ b4,
    const short* __restrict__ W1T, const float* __restrict__ b1,
    const short* __restrict__ W2T, const float* __restrict__ b2,
    const float* __restrict__ g6, const float* __restrict__ b6)
{
    __shared__ __align__(16) short As[64][256];   // y2 (bf16, swizzled)
    __shared__ __align__(16) short Hs[64][64];    // relu hidden chunk (swizzled)
    const int t = threadIdx.x;
    const int w = t >> 6, lane = t & 63;
    const int l31 = lane & 31, kg = lane >> 5;    // kg in {0,1}
    const size_t R0 = (size_t)blockIdx.x * 64;

    // --- Phase A: LN4(edge + y) -> bf16 As ---
    {
        const float4 gv = *(const float4*)&g4[lane * 4];
        const float4 bv = *(const float4*)&b4[lane * 4];
        const int gk = lane >> 1;
        for (int r = w * 16; r < w * 16 + 16; ++r) {
            const float4 e4 = *(const float4*)&EY[(R0 + r) * DIMC + lane * 4];
            const float4 y4 = *(const float4*)&Y[(R0 + r) * DIMC + lane * 4];
            float v0 = e4.x + y4.x, v1 = e4.y + y4.y, v2 = e4.z + y4.z, v3 = e4.w + y4.w;
            float mu = wave_sum(v0 + v1 + v2 + v3) * (1.f / DIMC);
            float d0 = v0 - mu, d1 = v1 - mu, d2 = v2 - mu, d3 = v3 - mu;
            float var = wave_sum(d0 * d0 + d1 * d1 + d2 * d2 + d3 * d3) * (1.f / DIMC);
            float rs = rsqrtf(var + 1e-5f);
            short* p = &As[r][(gk ^ (r & 7)) * 8 + (lane & 1) * 4];
            short4 s4;
            s4.x = f2bf(d0 * rs * gv.x + bv.x);
            s4.y = f2bf(d1 * rs * gv.y + bv.y);
            s4.z = f2bf(d2 * rs * gv.z + bv.z);
            s4.w = f2bf(d3 * rs * gv.w + bv.w);
            *(short4*)p = s4;
        }
    }
    __syncthreads();

    // --- GEMM phase ---
    const int tr1 = w & 1, tc1 = w >> 1;      // GEMM1: one 32x32 tile per wave
    const int arow1 = tr1 * 32 + l31;
    const int a1sw = arow1 & 7;
    const int r7 = l31 & 7;

    f32x16 acc2[4];
    #pragma unroll
    for (int a = 0; a < 4; ++a)
        #pragma unroll
        for (int i = 0; i < 16; ++i) acc2[a][i] = 0.f;

    const short* w2p0 = &W2T[(size_t)((2 * w + 0) * 32 + l31) * HID];
    const short* w2p1 = &W2T[(size_t)((2 * w + 1) * 32 + l31) * HID];

    for (int h = 0; h < 16; ++h) {
        // GEMM1: c1 = As(64x256) @ W1T-chunk -> 32x32 tile, K=256
        f32x16 c1;
        #pragma unroll
        for (int i = 0; i < 16; ++i) c1[i] = 0.f;
        const short* w1p = &W1T[(size_t)(h * 64 + tc1 * 32 + l31) * DIMC];
        #pragma unroll
        for (int ks = 0; ks < 16; ++ks) {
            const int gk = 2 * ks + kg;
            short8 a = *(const short8*)&As[arow1][(gk ^ a1sw) * 8];
            short8 b = *(const short8*)&w1p[gk * 8];
            c1 = __builtin_amdgcn_mfma_f32_32x32x16_bf16(a, b, c1, 0, 0, 0);
        }
        __syncthreads();   // prior GEMM2 reads of Hs complete
        {
            const float bb = b1[h * 64 + tc1 * 32 + l31];
            #pragma unroll
            for (int i = 0; i < 16; ++i) {
                const int row = tr1 * 32 + 4 * kg + (i & 3) + 8 * (i >> 2);
                const int hl = tc1 * 32 + l31;
                Hs[row][((hl >> 3) ^ (row & 7)) * 8 + (hl & 7)] = f2bf(fmaxf(c1[i] + bb, 0.f));
            }
        }
        __syncthreads();
        // GEMM2: acc2 += Hs(64x64) @ W2T-chunk, 4 tiles per wave
        #pragma unroll
        for (int ks = 0; ks < 4; ++ks) {
            const int gk = 2 * ks + kg;
            short8 a0 = *(const short8*)&Hs[l31][(gk ^ r7) * 8];
            short8 a1 = *(const short8*)&Hs[32 + l31][(gk ^ r7) * 8];
            const size_t kglob = (size_t)h * 64 + ks * 16 + kg * 8;
            short8 b0 = *(const short8*)&w2p0[kglob];
            short8 b1v = *(const short8*)&w2p1[kglob];
            acc2[0] = __builtin_amdgcn_mfma_f32_32x32x16_bf16(a0, b0,  acc2[0], 0, 0, 0);
            acc2[1] = __builtin_amdgcn_mfma_f32_32x32x16_bf16(a0, b1v, acc2[1], 0, 0, 0);
            acc2[2] = __builtin_amdgcn_mfma_f32_32x32x16_bf16(a1, b0,  acc2[2], 0, 0, 0);
            acc2[3] = __builtin_amdgcn_mfma_f32_32x32x16_bf16(a1, b1v, acc2[3], 0, 0, 0);
        }
    }
    __syncthreads();   // all GEMM1 As reads done before As overwrite

    // --- Epilogue: residual add (bf16, in LDS) ---
    #pragma unroll
    for (int a = 0; a < 4; ++a) {
        const int tr = a >> 1, tc2 = 2 * w + (a & 1);
        const int col = tc2 * 32 + l31;
        const float bb = b2[col];
        #pragma unroll
        for (int i = 0; i < 16; ++i) {
            const int row = tr * 32 + 4 * kg + (i & 3) + 8 * (i >> 2);
            const int phys = ((col >> 3) ^ (row & 7)) * 8 + (col & 7);
            As[row][phys] = f2bf(bf2f(As[row][phys]) + acc2[a][i] + bb);
        }
    }
    __syncthreads();

    // --- LN6 + store ---
    {
        const float4 gv = *(const float4*)&g6[lane * 4];
        const float4 bv = *(const float4*)&b6[lane * 4];
        const int gk = lane >> 1;
        for (int r = w * 16; r < w * 16 + 16; ++r) {
            const short4 s4 = *(const short4*)&As[r][(gk ^ (r & 7)) * 8 + (lane & 1) * 4];
            float v0 = bf2f(s4.x), v1 = bf2f(s4.y), v2 = bf2f(s4.z), v3 = bf2f(s4.w);
            float mu = wave_sum(v0 + v1 + v2 + v3) * (1.f / DIMC);
            float d0 = v0 - mu, d1 = v1 - mu, d2 = v2 - mu, d3 = v3 - mu;
            float var = wave_sum(d0 * d0 + d1 * d1 + d2 * d2 + d3 * d3) * (1.f / DIMC);
            float rs = rsqrtf(var + 1e-5f);
            float4 o;
            o.x = d0 * rs * gv.x + bv.x;
            o.y = d1 * rs * gv.y + bv.y;
            o.z = d2 * rs * gv.z + bv.z;
            o.w = d3 * rs * gv.w + bv.w;
            *(float4*)&EY[(R0 + r) * DIMC + lane * 4] = o;
        }
    }
}

// ---------------------------------------------------------------------------
extern "C" void kernel_launch(void* const* d_in, const int* in_sizes, int n_in,
                              void* d_out, int out_size, void* d_ws, size_t ws_size,
                              hipStream_t stream) {
    const float* x    = (const float*)d_in[0];
    const float* y    = (const float*)d_in[1];
    const float* Wq   = (const float*)d_in[3];  const float* bq  = (const float*)d_in[4];
    const float* Wk   = (const float*)d_in[5];  const float* bk  = (const float*)d_in[6];
    const float* Wv   = (const float*)d_in[7];  const float* bv  = (const float*)d_in[8];
    const float* We   = (const float*)d_in[9];  const float* be  = (const float*)d_in[10];
    const float* Woe  = (const float*)d_in[11]; const float* boe = (const float*)d_in[12];
    const float* Won  = (const float*)d_in[13]; const float* bon = (const float*)d_in[14];
    const float* ln1g = (const float*)d_in[15]; const float* ln1b = (const float*)d_in[16];
    const float* ln3g = (const float*)d_in[17]; const float* ln3b = (const float*)d_in[18];
    const float* ln4g = (const float*)d_in[19]; const float* ln4b = (const float*)d_in[20];
    const float* ln5g = (const float*)d_in[21]; const float* ln5b = (const float*)d_in[22];
    const float* ln6g = (const float*)d_in[23]; const float* ln6b = (const float*)d_in[24];
    const float* m1W1 = (const float*)d_in[25]; const float* m1b1 = (const float*)d_in[26];
    const float* m1W2 = (const float*)d_in[27]; const float* m1b2 = (const float*)d_in[28];
    const float* m2W1 = (const float*)d_in[29]; const float* m2b1 = (const float*)d_in[30];
    const float* m2W2 = (const float*)d_in[31]; const float* m2b2 = (const float*)d_in[32];

    float* outx = (float*)d_out;
    float* outy = (float*)d_out + NB * NSEQ * DIMC;

    float* ws  = (float*)d_ws;
    float* X1  = ws;
    float* Q   = ws + 262144;
    float* K   = ws + 524288;
    float* V   = ws + 786432;
    float* ATT = ws + 1048576;          // 33554432 floats (134 MB)
    // bf16 transposed weights carved from the ATT region (ATT is dead after
    // k_node_x; transposes run after it, before k_mlp_y2).
    short* W1T = (short*)ATT;                 // 1024x256 bf16
    short* W2T = (short*)ATT + 262144;        // 256x1024 bf16

    k_ln_qkv<<<NB * NSEQ, 256, 0, stream>>>(x, ln1g, ln1b, Wq, bq, Wk, bk, Wv, bv, X1, Q, K, V);
    k_e_attn<<<dim3(EROWS / BM, DIMC / BN), 256, 0, stream>>>(y, We, be, Q, K, ATT);
    k_edge<<<dim3(EROWS / BM, DIMC / BN), 256, 0, stream>>>(ATT, Woe, boe, outy);
    k_node_x<<<NB * NSEQ, 256, 0, stream>>>(ATT, V, X1, Won, bon, ln3g, ln3b,
                                            m1W1, m1b1, m1W2, m1b2, ln5g, ln5b, outx);
    k_transpose_bf16<<<dim3(HID / 32, DIMC / 32), 256, 0, stream>>>(m2W1, W1T, DIMC, HID);
    k_transpose_bf16<<<dim3(DIMC / 32, HID / 32), 256, 0, stream>>>(m2W2, W2T, HID, DIMC);
    k_mlp_y2<<<EROWS / 64, 256, 0, stream>>>(outy, y, ln4g, ln4b,
                                             W1T, m2b1, W2T, m2b2, ln6g, ln6b);
}

// Round 3
// 1130.433 us; speedup vs baseline: 5.3071x; 1.2699x over previous
//
#include <hip/hip_runtime.h>
#include <hip/hip_bf16.h>

// ---------------------------------------------------------------------------
// Encoder block. B=8, N=128, DIM=256, HEADS=8, dk=32, HID=1024.
// R3: e-attn and edge GEMMs -> bf16 MFMA; ATT stored bf16; y-MLP restructured
// to 1 barrier/chunk with double-buffered Hs and split GEMM1 chains.
// ---------------------------------------------------------------------------

#define DIMC 256
#define NSEQ 128
#define NB 8
#define HID 1024
#define EROWS (NB * NSEQ * NSEQ)   // 131072

typedef __attribute__((ext_vector_type(8)))  short short8;
typedef __attribute__((ext_vector_type(16))) float f32x16;

__device__ __forceinline__ short f2bf(float f) {
    union { float f; unsigned u; } v; v.f = f;
    unsigned r = (v.u + 0x7FFF + ((v.u >> 16) & 1)) >> 16;
    return (short)r;
}
__device__ __forceinline__ float bf2f(short s) {
    union { unsigned u; float f; } v; v.u = ((unsigned)(unsigned short)s) << 16;
    return v.f;
}

__device__ __forceinline__ float wave_sum(float v) {
    #pragma unroll
    for (int o = 32; o; o >>= 1) v += __shfl_xor(v, o, 64);
    return v;
}

__device__ __forceinline__ float block_reduce_sum(float v, float* sc, int t) {
    #pragma unroll
    for (int o = 32; o > 0; o >>= 1) v += __shfl_down(v, o, 64);
    __syncthreads();
    if ((t & 63) == 0) sc[t >> 6] = v;
    __syncthreads();
    return sc[0] + sc[1] + sc[2] + sc[3];
}

// ---------------------------------------------------------------------------
// Kernel 1: x1 = LN1(x); q/k/v = x1 @ W{q,k,v} + b.  One block per (b,i) row.
// ---------------------------------------------------------------------------
__global__ __launch_bounds__(256, 2) void k_ln_qkv(
    const float* __restrict__ X, const float* __restrict__ g, const float* __restrict__ be,
    const float* __restrict__ Wq, const float* __restrict__ bq,
    const float* __restrict__ Wk, const float* __restrict__ bk,
    const float* __restrict__ Wv, const float* __restrict__ bv,
    float* __restrict__ X1, float* __restrict__ Q, float* __restrict__ K, float* __restrict__ V)
{
    __shared__ float xs[DIMC];
    __shared__ float red[4];
    const int t = threadIdx.x;
    const int row = blockIdx.x;
    float v = X[(size_t)row * DIMC + t];
    float mu = block_reduce_sum(v, red, t) * (1.f / DIMC);
    float d = v - mu;
    float var = block_reduce_sum(d * d, red, t) * (1.f / DIMC);
    float x1v = d * rsqrtf(var + 1e-5f) * g[t] + be[t];
    xs[t] = x1v;
    X1[(size_t)row * DIMC + t] = x1v;
    __syncthreads();
    float aq = bq[t], ak = bk[t], av = bv[t];
    #pragma unroll 4
    for (int k2 = 0; k2 < DIMC; ++k2) {
        float xv = xs[k2];
        aq = fmaf(xv, Wq[k2 * DIMC + t], aq);
        ak = fmaf(xv, Wk[k2 * DIMC + t], ak);
        av = fmaf(xv, Wv[k2 * DIMC + t], av);
    }
    Q[(size_t)row * DIMC + t] = aq;
    K[(size_t)row * DIMC + t] = ak;
    V[(size_t)row * DIMC + t] = av;
}

// ---------------------------------------------------------------------------
// Transpose + fp32->bf16 convert: dst[N][M] = bf16(src[M][N]).
// ---------------------------------------------------------------------------
__global__ __launch_bounds__(256) void k_transpose_bf16(
    const float* __restrict__ src, short* __restrict__ dst, int M, int N)
{
    __shared__ short tile[32][33];
    const int t = threadIdx.x, tx = t & 31, ty = t >> 5;
    const int bx = blockIdx.x, by = blockIdx.y;
    #pragma unroll
    for (int r = ty; r < 32; r += 8)
        tile[r][tx] = f2bf(src[(size_t)(by * 32 + r) * N + bx * 32 + tx]);
    __syncthreads();
    #pragma unroll
    for (int r = ty; r < 32; r += 8)
        dst[(size_t)(bx * 32 + r) * M + by * 32 + tx] = tile[tx][r];
}

// ---------------------------------------------------------------------------
// k_e_attn_m: e = Y @ We + be (bf16 MFMA, 64 rows x 256 cols per block);
// epilogue: attn = (q*k/sqrt(32))*(e+1)*e -> ATTb (bf16).
// ---------------------------------------------------------------------------
__global__ __launch_bounds__(256, 2) void k_e_attn_m(
    const float* __restrict__ Y, const short* __restrict__ WeT,
    const float* __restrict__ be,
    const float* __restrict__ Q, const float* __restrict__ Kp,
    short* __restrict__ ATTb)
{
    __shared__ __align__(16) short As[64][256];
    const int t = threadIdx.x, w = t >> 6, lane = t & 63;
    const int l31 = lane & 31, kg = lane >> 5;
    const size_t R0 = (size_t)blockIdx.x * 64;

    // stage Y tile -> bf16 swizzled LDS
    for (int r = w * 16; r < w * 16 + 16; ++r) {
        float4 y4 = *(const float4*)&Y[(R0 + r) * DIMC + lane * 4];
        short4 s4;
        s4.x = f2bf(y4.x); s4.y = f2bf(y4.y); s4.z = f2bf(y4.z); s4.w = f2bf(y4.w);
        *(short4*)&As[r][(((lane >> 1) ^ (r & 7)) << 3) + (lane & 1) * 4] = s4;
    }
    __syncthreads();

    const int rh = (w & 1) * 32, cbase = (w >> 1) * 128;
    const int sw = l31 & 7;
    f32x16 acc[4];
    #pragma unroll
    for (int a = 0; a < 4; ++a)
        #pragma unroll
        for (int i = 0; i < 16; ++i) acc[a][i] = 0.f;

    #pragma unroll
    for (int ks = 0; ks < 16; ++ks) {
        const int gk = 2 * ks + kg;
        short8 a = *(const short8*)&As[rh + l31][(gk ^ sw) * 8];
        #pragma unroll
        for (int tt = 0; tt < 4; ++tt) {
            short8 b = *(const short8*)&WeT[(size_t)(cbase + tt * 32 + l31) * DIMC + gk * 8];
            acc[tt] = __builtin_amdgcn_mfma_f32_32x32x16_bf16(a, b, acc[tt], 0, 0, 0);
        }
    }

    const int m0 = (int)(R0);
    const int qrow = m0 >> 7, bidx = m0 >> 14, jb = m0 & 127;
    const float isq = 0.17677669529663687f;   // 1/sqrt(32)
    #pragma unroll
    for (int tt = 0; tt < 4; ++tt) {
        const int n = cbase + tt * 32 + l31;
        const float qv = Q[(size_t)qrow * DIMC + n];
        const float bb = be[n];
        #pragma unroll
        for (int i = 0; i < 16; ++i) {
            const int row = rh + 4 * kg + (i & 3) + 8 * (i >> 2);
            const float kv = Kp[(size_t)((bidx << 7) + jb + row) * DIMC + n];
            const float e = acc[tt][i] + bb;
            const float qk = qv * kv * isq;
            ATTb[(size_t)(m0 + row) * DIMC + n] = f2bf(qk * (e + 1.f) * e);
        }
    }
}

// ---------------------------------------------------------------------------
// k_edge_m: edge = ATTb @ Woe + boe (bf16 MFMA) -> EY fp32 (d_out y-region).
// ---------------------------------------------------------------------------
__global__ __launch_bounds__(256, 2) void k_edge_m(
    const short* __restrict__ ATTb, const short* __restrict__ WoeT,
    const float* __restrict__ boe, float* __restrict__ EDGE)
{
    __shared__ __align__(16) short As[64][256];
    const int t = threadIdx.x, w = t >> 6, lane = t & 63;
    const int l31 = lane & 31, kg = lane >> 5;
    const size_t R0 = (size_t)blockIdx.x * 64;

    // stage ATT tile (already bf16), 2 rows per wave-inst
    #pragma unroll
    for (int it = 0; it < 8; ++it) {
        const int r = w * 16 + it * 2 + kg;
        short8 v = *(const short8*)&ATTb[(R0 + r) * DIMC + l31 * 8];
        *(short8*)&As[r][((l31 ^ (r & 7))) * 8] = v;
    }
    __syncthreads();

    const int rh = (w & 1) * 32, cbase = (w >> 1) * 128;
    const int sw = l31 & 7;
    f32x16 acc[4];
    #pragma unroll
    for (int a = 0; a < 4; ++a)
        #pragma unroll
        for (int i = 0; i < 16; ++i) acc[a][i] = 0.f;

    #pragma unroll
    for (int ks = 0; ks < 16; ++ks) {
        const int gk = 2 * ks + kg;
        short8 a = *(const short8*)&As[rh + l31][(gk ^ sw) * 8];
        #pragma unroll
        for (int tt = 0; tt < 4; ++tt) {
            short8 b = *(const short8*)&WoeT[(size_t)(cbase + tt * 32 + l31) * DIMC + gk * 8];
            acc[tt] = __builtin_amdgcn_mfma_f32_32x32x16_bf16(a, b, acc[tt], 0, 0, 0);
        }
    }

    const int m0 = (int)(R0);
    #pragma unroll
    for (int tt = 0; tt < 4; ++tt) {
        const int n = cbase + tt * 32 + l31;
        const float bb = boe[n];
        #pragma unroll
        for (int i = 0; i < 16; ++i) {
            const int row = rh + 4 * kg + (i & 3) + 8 * (i >> 2);
            EDGE[(size_t)(m0 + row) * DIMC + n] = acc[tt][i] + bb;
        }
    }
}

// ---------------------------------------------------------------------------
// Kernel 4: x-path tail. ATT now bf16.
// ---------------------------------------------------------------------------
__global__ __launch_bounds__(256, 2) void k_node_x(
    const short* __restrict__ ATTb, const float* __restrict__ V,
    const float* __restrict__ X1,
    const float* __restrict__ Won, const float* __restrict__ bon,
    const float* __restrict__ g3, const float* __restrict__ b3,
    const float* __restrict__ W1, const float* __restrict__ b1,
    const float* __restrict__ W2, const float* __restrict__ b2,
    const float* __restrict__ g5, const float* __restrict__ b5,
    float* __restrict__ OUTX)
{
    __shared__ float ns[DIMC];
    __shared__ float x2s[DIMC];
    __shared__ float hs[HID];
    __shared__ float red[4];
    const int t = threadIdx.x;
    const int bi = blockIdx.x;
    const int b = bi >> 7;
    const short* arow = ATTb + (size_t)bi * NSEQ * DIMC + t;
    const float* vbase = V + (size_t)b * NSEQ * DIMC + t;
    float mx = -3.4e38f, l = 0.f, acc = 0.f;
    for (int j = 0; j < NSEQ; ++j) {
        float a = bf2f(arow[(size_t)j * DIMC]);
        float vv = vbase[(size_t)j * DIMC];
        if (a > mx) { float sc = __expf(mx - a); l *= sc; acc *= sc; mx = a; }
        float p = __expf(a - mx);
        l += p;
        acc = fmaf(p, vv, acc);
    }
    ns[t] = acc / l;
    __syncthreads();
    float o = bon[t];
    #pragma unroll 4
    for (int k2 = 0; k2 < DIMC; ++k2) o = fmaf(ns[k2], Won[k2 * DIMC + t], o);
    float resid = X1[(size_t)bi * DIMC + t] + o;
    float mu = block_reduce_sum(resid, red, t) * (1.f / DIMC);
    float d = resid - mu;
    float var = block_reduce_sum(d * d, red, t) * (1.f / DIMC);
    float x2 = d * rsqrtf(var + 1e-5f) * g3[t] + b3[t];
    x2s[t] = x2;
    __syncthreads();
    float4 h = *(const float4*)&b1[t * 4];
    for (int k2 = 0; k2 < DIMC; ++k2) {
        float xv = x2s[k2];
        float4 w = *(const float4*)&W1[(size_t)k2 * HID + t * 4];
        h.x = fmaf(xv, w.x, h.x); h.y = fmaf(xv, w.y, h.y);
        h.z = fmaf(xv, w.z, h.z); h.w = fmaf(xv, w.w, h.w);
    }
    h.x = fmaxf(h.x, 0.f); h.y = fmaxf(h.y, 0.f); h.z = fmaxf(h.z, 0.f); h.w = fmaxf(h.w, 0.f);
    *(float4*)&hs[t * 4] = h;
    __syncthreads();
    float o2 = b2[t];
    #pragma unroll 4
    for (int hh = 0; hh < HID; ++hh) o2 = fmaf(hs[hh], W2[(size_t)hh * DIMC + t], o2);
    float r2 = x2 + o2;
    float mu2 = block_reduce_sum(r2, red, t) * (1.f / DIMC);
    float d2 = r2 - mu2;
    float v2 = block_reduce_sum(d2 * d2, red, t) * (1.f / DIMC);
    OUTX[(size_t)bi * DIMC + t] = d2 * rsqrtf(v2 + 1e-5f) * g5[t] + b5[t];
}

// ---------------------------------------------------------------------------
// Kernel 5 (R3): fused y-path tail, double-buffered Hs, 1 barrier/chunk.
// ---------------------------------------------------------------------------
__global__ __launch_bounds__(256, 2) void k_mlp_y3(
    float* __restrict__ EY, const float* __restrict__ Y,
    const float* __restrict__ g4, const float* __restrict__ b4,
    const short* __restrict__ W1T, const float* __restrict__ b1,
    const short* __restrict__ W2T, const float* __restrict__ b2,
    const float* __restrict__ g6, const float* __restrict__ b6)
{
    __shared__ __align__(16) short As[64][256];     // y2 (bf16, swizzled)
    __shared__ __align__(16) short Hs[2][64][64];   // relu hidden, double-buffered
    const int t = threadIdx.x;
    const int w = t >> 6, lane = t & 63;
    const int l31 = lane & 31, kg = lane >> 5;
    const size_t R0 = (size_t)blockIdx.x * 64;

    // --- Phase A: LN4(edge + y) -> bf16 As ---
    {
        const float4 gv = *(const float4*)&g4[lane * 4];
        const float4 bv = *(const float4*)&b4[lane * 4];
        const int gk = lane >> 1;
        for (int r = w * 16; r < w * 16 + 16; ++r) {
            const float4 e4 = *(const float4*)&EY[(R0 + r) * DIMC + lane * 4];
            const float4 y4 = *(const float4*)&Y[(R0 + r) * DIMC + lane * 4];
            float v0 = e4.x + y4.x, v1 = e4.y + y4.y, v2 = e4.z + y4.z, v3 = e4.w + y4.w;
            float mu = wave_sum(v0 + v1 + v2 + v3) * (1.f / DIMC);
            float d0 = v0 - mu, d1 = v1 - mu, d2 = v2 - mu, d3 = v3 - mu;
            float var = wave_sum(d0 * d0 + d1 * d1 + d2 * d2 + d3 * d3) * (1.f / DIMC);
            float rs = rsqrtf(var + 1e-5f);
            short* p = &As[r][(gk ^ (r & 7)) * 8 + (lane & 1) * 4];
            short4 s4;
            s4.x = f2bf(d0 * rs * gv.x + bv.x);
            s4.y = f2bf(d1 * rs * gv.y + bv.y);
            s4.z = f2bf(d2 * rs * gv.z + bv.z);
            s4.w = f2bf(d3 * rs * gv.w + bv.w);
            *(short4*)p = s4;
        }
    }
    __syncthreads();

    const int tr1 = w & 1, tc1 = w >> 1;
    const int arow1 = tr1 * 32 + l31;
    const int a1sw = l31 & 7;
    const int r7 = l31 & 7;
    const int hcol = tc1 * 32 + l31;

    f32x16 acc2[4];
    #pragma unroll
    for (int a = 0; a < 4; ++a)
        #pragma unroll
        for (int i = 0; i < 16; ++i) acc2[a][i] = 0.f;

    const short* w2p0 = &W2T[(size_t)((2 * w + 0) * 32 + l31) * HID];
    const short* w2p1 = &W2T[(size_t)((2 * w + 1) * 32 + l31) * HID];

    // GEMM1 for chunk h -> Hs[h&1] (two independent K-chains)
    auto gemm1 = [&](int h) {
        const short* w1p = &W1T[(size_t)(h * 64 + hcol) * DIMC];
        f32x16 c1a, c1b;
        #pragma unroll
        for (int i = 0; i < 16; ++i) { c1a[i] = 0.f; c1b[i] = 0.f; }
        #pragma unroll
        for (int ks = 0; ks < 8; ++ks) {
            const int gk = 2 * ks + kg;
            short8 a = *(const short8*)&As[arow1][(gk ^ a1sw) * 8];
            short8 b = *(const short8*)&w1p[gk * 8];
            c1a = __builtin_amdgcn_mfma_f32_32x32x16_bf16(a, b, c1a, 0, 0, 0);
        }
        #pragma unroll
        for (int ks = 8; ks < 16; ++ks) {
            const int gk = 2 * ks + kg;
            short8 a = *(const short8*)&As[arow1][(gk ^ a1sw) * 8];
            short8 b = *(const short8*)&w1p[gk * 8];
            c1b = __builtin_amdgcn_mfma_f32_32x32x16_bf16(a, b, c1b, 0, 0, 0);
        }
        const float bb = b1[h * 64 + hcol];
        short (*Hw)[64] = Hs[h & 1];
        #pragma unroll
        for (int i = 0; i < 16; ++i) {
            const int row = tr1 * 32 + 4 * kg + (i & 3) + 8 * (i >> 2);
            Hw[row][(((hcol >> 3) ^ (row & 7)) << 3) + (hcol & 7)] =
                f2bf(fmaxf(c1a[i] + c1b[i] + bb, 0.f));
        }
    };
    // GEMM2 for chunk h (reads Hs[h&1])
    auto gemm2 = [&](int h) {
        const short (*Hr)[64] = Hs[h & 1];
        #pragma unroll
        for (int ks = 0; ks < 4; ++ks) {
            const int gk = 2 * ks + kg;
            short8 a0 = *(const short8*)&Hr[l31][(gk ^ r7) * 8];
            short8 a1 = *(const short8*)&Hr[32 + l31][(gk ^ r7) * 8];
            const size_t kglob = (size_t)h * 64 + ks * 16 + kg * 8;
            short8 b0 = *(const short8*)&w2p0[kglob];
            short8 b1v = *(const short8*)&w2p1[kglob];
            acc2[0] = __builtin_amdgcn_mfma_f32_32x32x16_bf16(a0, b0,  acc2[0], 0, 0, 0);
            acc2[1] = __builtin_amdgcn_mfma_f32_32x32x16_bf16(a0, b1v, acc2[1], 0, 0, 0);
            acc2[2] = __builtin_amdgcn_mfma_f32_32x32x16_bf16(a1, b0,  acc2[2], 0, 0, 0);
            acc2[3] = __builtin_amdgcn_mfma_f32_32x32x16_bf16(a1, b1v, acc2[3], 0, 0, 0);
        }
    };

    gemm1(0);
    __syncthreads();
    for (int h = 1; h < 16; ++h) {
        gemm2(h - 1);
        gemm1(h);
        __syncthreads();
    }
    gemm2(15);

    // --- Epilogue: residual add (bf16, in LDS) ---
    #pragma unroll
    for (int a = 0; a < 4; ++a) {
        const int tr = a >> 1, tc2 = 2 * w + (a & 1);
        const int col = tc2 * 32 + l31;
        const float bb = b2[col];
        #pragma unroll
        for (int i = 0; i < 16; ++i) {
            const int row = tr * 32 + 4 * kg + (i & 3) + 8 * (i >> 2);
            const int phys = ((col >> 3) ^ (row & 7)) * 8 + (col & 7);
            As[row][phys] = f2bf(bf2f(As[row][phys]) + acc2[a][i] + bb);
        }
    }
    __syncthreads();

    // --- LN6 + store ---
    {
        const float4 gv = *(const float4*)&g6[lane * 4];
        const float4 bv = *(const float4*)&b6[lane * 4];
        const int gk = lane >> 1;
        for (int r = w * 16; r < w * 16 + 16; ++r) {
            const short4 s4 = *(const short4*)&As[r][(gk ^ (r & 7)) * 8 + (lane & 1) * 4];
            float v0 = bf2f(s4.x), v1 = bf2f(s4.y), v2 = bf2f(s4.z), v3 = bf2f(s4.w);
            float mu = wave_sum(v0 + v1 + v2 + v3) * (1.f / DIMC);
            float d0 = v0 - mu, d1 = v1 - mu, d2 = v2 - mu, d3 = v3 - mu;
            float var = wave_sum(d0 * d0 + d1 * d1 + d2 * d2 + d3 * d3) * (1.f / DIMC);
            float rs = rsqrtf(var + 1e-5f);
            float4 o;
            o.x = d0 * rs * gv.x + bv.x;
            o.y = d1 * rs * gv.y + bv.y;
            o.z = d2 * rs * gv.z + bv.z;
            o.w = d3 * rs * gv.w + bv.w;
            *(float4*)&EY[(R0 + r) * DIMC + lane * 4] = o;
        }
    }
}

// ---------------------------------------------------------------------------
extern "C" void kernel_launch(void* const* d_in, const int* in_sizes, int n_in,
                              void* d_out, int out_size, void* d_ws, size_t ws_size,
                              hipStream_t stream) {
    const float* x    = (const float*)d_in[0];
    const float* y    = (const float*)d_in[1];
    const float* Wq   = (const float*)d_in[3];  const float* bq  = (const float*)d_in[4];
    const float* Wk   = (const float*)d_in[5];  const float* bk  = (const float*)d_in[6];
    const float* Wv   = (const float*)d_in[7];  const float* bv  = (const float*)d_in[8];
    const float* We   = (const float*)d_in[9];  const float* be  = (const float*)d_in[10];
    const float* Woe  = (const float*)d_in[11]; const float* boe = (const float*)d_in[12];
    const float* Won  = (const float*)d_in[13]; const float* bon = (const float*)d_in[14];
    const float* ln1g = (const float*)d_in[15]; const float* ln1b = (const float*)d_in[16];
    const float* ln3g = (const float*)d_in[17]; const float* ln3b = (const float*)d_in[18];
    const float* ln4g = (const float*)d_in[19]; const float* ln4b = (const float*)d_in[20];
    const float* ln5g = (const float*)d_in[21]; const float* ln5b = (const float*)d_in[22];
    const float* ln6g = (const float*)d_in[23]; const float* ln6b = (const float*)d_in[24];
    const float* m1W1 = (const float*)d_in[25]; const float* m1b1 = (const float*)d_in[26];
    const float* m1W2 = (const float*)d_in[27]; const float* m1b2 = (const float*)d_in[28];
    const float* m2W1 = (const float*)d_in[29]; const float* m2b1 = (const float*)d_in[30];
    const float* m2W2 = (const float*)d_in[31]; const float* m2b2 = (const float*)d_in[32];

    float* outx = (float*)d_out;
    float* outy = (float*)d_out + NB * NSEQ * DIMC;

    float* ws  = (float*)d_ws;
    float* X1  = ws;                    // 262144 floats each
    float* Q   = ws + 262144;
    float* K   = ws + 524288;
    float* V   = ws + 786432;
    short* wsS = (short*)(ws + 1048576);
    short* WeT  = wsS;                  //  65536 shorts (256x256)
    short* WoeT = wsS + 65536;          //  65536
    short* W1T  = wsS + 131072;         // 262144 (1024x256)
    short* W2T  = wsS + 393216;         // 262144 (256x1024)
    short* ATTb = wsS + 655360;         // 33554432 shorts (67 MB)

    // weight prep (bf16 transposes)
    k_transpose_bf16<<<dim3(8, 8),  256, 0, stream>>>(We,   WeT,  DIMC, DIMC);
    k_transpose_bf16<<<dim3(8, 8),  256, 0, stream>>>(Woe,  WoeT, DIMC, DIMC);
    k_transpose_bf16<<<dim3(32, 8), 256, 0, stream>>>(m2W1, W1T,  DIMC, HID);
    k_transpose_bf16<<<dim3(8, 32), 256, 0, stream>>>(m2W2, W2T,  HID,  DIMC);

    k_ln_qkv<<<NB * NSEQ, 256, 0, stream>>>(x, ln1g, ln1b, Wq, bq, Wk, bk, Wv, bv, X1, Q, K, V);
    k_e_attn_m<<<EROWS / 64, 256, 0, stream>>>(y, WeT, be, Q, K, ATTb);
    k_edge_m<<<EROWS / 64, 256, 0, stream>>>(ATTb, WoeT, boe, outy);
    k_node_x<<<NB * NSEQ, 256, 0, stream>>>(ATTb, V, X1, Won, bon, ln3g, ln3b,
                                            m1W1, m1b1, m1W2, m1b2, ln5g, ln5b, outx);
    k_mlp_y3<<<EROWS / 64, 256, 0, stream>>>(outy, y, ln4g, ln4b,
                                             W1T, m2b1, W2T, m2b2, ln6g, ln6b);
}